// Round 19
// baseline (157.011 us; speedup 1.0000x reference)
//
#include <hip/hip_runtime.h>

// MHA: out = softmax(mask(QK^T/8)) V, with Q/K/V/out linear projections.
// B=2, T=2048, D=1024, H=16, d_k=64.
// R19: split-K attention. Fixed-max softmax (m=12 const) makes partials
//      trivially additive: O = sum_z O_z, l = sum_z l_z (no max merge).
//      attn grid x2 (z = key-half) -> 4 blocks/CU, 8 waves/SIMD (was 4),
//      doubling latency hiding on the 25% both-pipes-idle stall. Partials
//      f32 to ws; tiny reduce_o kernel combines + converts to bf16.
//      Loop body / staging / sync byte-frozen from R18.

#define T_SEQ 2048
#define NH 16
#define DM 1024
#define DK 64

typedef __attribute__((ext_vector_type(8))) short bf16x8;
typedef __attribute__((ext_vector_type(4))) float f32x4;
typedef __attribute__((ext_vector_type(4))) unsigned short u16x4;
typedef __attribute__((ext_vector_type(4))) unsigned int u32x4;

__device__ __forceinline__ unsigned short f2bf(float x) {
  union { float f; unsigned int u; } v; v.f = x;
  unsigned int r = v.u + 0x7fffu + ((v.u >> 16) & 1u);  // RNE
  return (unsigned short)(r >> 16);
}
__device__ __forceinline__ float bf2f(unsigned short h) {
  union { unsigned int u; float f; } v; v.u = ((unsigned int)h) << 16;
  return v.f;
}
__device__ __forceinline__ void gload16(const unsigned short* g, unsigned short* l) {
  __builtin_amdgcn_global_load_lds(
      (const __attribute__((address_space(1))) void*)(g),
      (__attribute__((address_space(3))) void*)(l), 16, 0, 0);
}
__device__ __forceinline__ unsigned int cvtpk(float a, float b) {
  unsigned int r;
  asm("v_cvt_pk_bf16_f32 %0, %1, %2" : "=v"(r) : "v"(a), "v"(b));
  return r;
}

// ------- fused prep: weights cvt + activations cvt + mask pack -------
__global__ __launch_bounds__(256) void prep_all(
    const float* __restrict__ Wq, const float* __restrict__ Wk,
    const float* __restrict__ Wv, const float* __restrict__ Wo,
    const float* __restrict__ q, const float* __restrict__ k,
    const float* __restrict__ v,
    const int* __restrict__ am, const int* __restrict__ kpm,
    unsigned short* __restrict__ wq, unsigned short* __restrict__ wk,
    unsigned short* __restrict__ wv, unsigned short* __restrict__ woh,
    unsigned short* __restrict__ qb, unsigned short* __restrict__ kb,
    unsigned short* __restrict__ vb,
    unsigned long long* __restrict__ pm) {
  const int id = blockIdx.x;
  if (id < 4096) {
    const int z = id >> 10;
    const int i = (id & 1023) * 256 + threadIdx.x;
    const float* src = (z == 0) ? Wq : (z == 1) ? Wk : (z == 2) ? Wv : Wo;
    unsigned short* dst = (z == 0) ? wq : (z == 1) ? wk : (z == 2) ? wv : woh;
    f32x4 x = ((const f32x4*)src)[i];
    u16x4 h;
#pragma unroll
    for (int j = 0; j < 4; ++j) h[j] = f2bf(x[j]);
    ((u16x4*)dst)[i] = h;
  } else if (id < 16384) {
    const int t = id - 4096;
    const int z = t >> 12;
    const int i = (t & 4095) * 256 + threadIdx.x;
    const float* src = (z == 0) ? q : (z == 1) ? k : v;
    unsigned short* dst = (z == 0) ? qb : (z == 1) ? kb : vb;
    f32x4 x = ((const f32x4*)src)[i];
    u16x4 h;
#pragma unroll
    for (int j = 0; j < 4; ++j) h[j] = f2bf(x[j]);
    ((u16x4*)dst)[i] = h;
  } else {
    const int w = (id - 16384) * 4 + ((int)threadIdx.x >> 6);
    const int lane = threadIdx.x & 63;
    const int kt = w & 31;
    const int qq = (w >> 5) & 2047;
    const int b = w >> 16;
    const int col = kt * 64 + lane;
    int masked = am[((long)(b * T_SEQ + qq)) * T_SEQ + col] | kpm[b * T_SEQ + col];
    unsigned long long bits = __ballot(masked != 0);
    if (lane == 0) pm[((long)(b * T_SEQ + qq)) * 32 + kt] = bits;
  }
}

// ---------------- GEMM: C = A @ B^T + bias (A,B bf16 in HBM) --------------
template <int EPI, int TERMS, int WM, int WN, int BN>
__device__ __forceinline__ void gemm_body(
    const unsigned short* __restrict__ Ahi,
    const unsigned short* __restrict__ Bhi, const unsigned short* __restrict__ Blo,
    const float* __restrict__ bias, unsigned short* __restrict__ Chi,
    float* __restrict__ Cf, unsigned short* __restrict__ Vt, int m0, int n0) {
  constexpr int FM = 128 / (WM * 16);
  constexpr int FN = BN / (WN * 16);
  constexpr int AIT = 2;
  constexpr int BIT = (BN * 4) / 256;
  __shared__ alignas(16) unsigned short sAh[2][128 * 32];
  __shared__ alignas(16) unsigned short sBh[2][BN * 32];
  __shared__ alignas(16) unsigned short sBl[TERMS == 2 ? 2 : 1][TERMS == 2 ? BN * 32 : 8];

  const int tid = threadIdx.x;
  const int lane = tid & 63, wid = tid >> 6;
  const int lr = lane & 15, lg = lane >> 4;
  const int wr = wid / WN, wc = wid % WN;

  f32x4 acc[FM][FN];
#pragma unroll
  for (int i = 0; i < FM; ++i)
#pragma unroll
    for (int j = 0; j < FN; ++j) acc[i][j] = (f32x4){0.f, 0.f, 0.f, 0.f};

  long asrc[AIT], bsrc[BIT];
#pragma unroll
  for (int it = 0; it < AIT; ++it) {
    int c = it * 256 + tid, r = c >> 2;
    int scb = (c & 3) ^ ((r >> 1) & 3);
    asrc[it] = (long)(m0 + r) * DM + scb * 8;
  }
#pragma unroll
  for (int it = 0; it < BIT; ++it) {
    int c = it * 256 + tid, r = c >> 2;
    int scb = (c & 3) ^ ((r >> 1) & 3);
    bsrc[it] = (long)(n0 + r) * DM + scb * 8;
  }

  auto stage = [&](int bi, int kt) {
#pragma unroll
    for (int it = 0; it < AIT; ++it)
      gload16(Ahi + asrc[it] + kt * 32, &sAh[bi][it * 2048 + wid * 512]);
#pragma unroll
    for (int it = 0; it < BIT; ++it) {
      const int dst = it * 2048 + wid * 512;
      gload16(Bhi + bsrc[it] + kt * 32, &sBh[bi][dst]);
      if constexpr (TERMS == 2) gload16(Blo + bsrc[it] + kt * 32, &sBl[bi][dst]);
    }
  };

  stage(0, 0);
  __syncthreads();
  int buf = 0;

  for (int kt = 0; kt < DM / 32; ++kt) {
    if (kt < DM / 32 - 1) stage(buf ^ 1, kt + 1);

    bf16x8 afh[FM], bfh[FN], bfl[FN];
#pragma unroll
    for (int f = 0; f < FM; ++f) {
      int rA = wr * (FM * 16) + f * 16 + lr;
      int iA = rA * 32 + ((lg ^ ((rA >> 1) & 3)) << 3);
      afh[f] = *(const bf16x8*)&sAh[buf][iA];
    }
#pragma unroll
    for (int f = 0; f < FN; ++f) {
      int rB = wc * (FN * 16) + f * 16 + lr;
      int iB = rB * 32 + ((lg ^ ((rB >> 1) & 3)) << 3);
      bfh[f] = *(const bf16x8*)&sBh[buf][iB];
      if constexpr (TERMS == 2) bfl[f] = *(const bf16x8*)&sBl[buf][iB];
    }
#pragma unroll
    for (int fm = 0; fm < FM; ++fm)
#pragma unroll
      for (int fn = 0; fn < FN; ++fn) {
        acc[fm][fn] = __builtin_amdgcn_mfma_f32_16x16x32_bf16(afh[fm], bfh[fn], acc[fm][fn], 0, 0, 0);
        if constexpr (TERMS == 2)
          acc[fm][fn] = __builtin_amdgcn_mfma_f32_16x16x32_bf16(afh[fm], bfl[fn], acc[fm][fn], 0, 0, 0);
      }
    __syncthreads();
    buf ^= 1;
  }

#pragma unroll
  for (int fm = 0; fm < FM; ++fm)
#pragma unroll
    for (int fn = 0; fn < FN; ++fn) {
      const int mb = m0 + wr * (FM * 16) + fm * 16 + lg * 4;
      const int n = n0 + wc * (FN * 16) + fn * 16 + lr;
      float y[4];
#pragma unroll
      for (int i = 0; i < 4; ++i) y[i] = acc[fm][fn][i] + bias[n];
      if constexpr (EPI == 0) {
        if (Vt) {
          // V^T: [bh][d][t], 4 consecutive t -> one 8B store
          int b = mb >> 11, t0 = mb & 2047, hh_ = n >> 6, d = n & 63;
          uint2 w = make_uint2(cvtpk(y[0], y[1]), cvtpk(y[2], y[3]));
          *(uint2*)(Vt + ((long)((b * NH + hh_) * DK + d)) * T_SEQ + t0) = w;
        } else {
#pragma unroll
          for (int i = 0; i < 4; ++i) {
            int m = mb + i;
            int b = m >> 11, t = m & 2047, hh_ = n >> 6, d = n & 63;
            Chi[((long)((b * NH + hh_) * T_SEQ + t)) * DK + d] = f2bf(y[i]);
          }
        }
      } else {
#pragma unroll
        for (int i = 0; i < 4; ++i) Cf[(long)(mb + i) * DM + n] = y[i];
      }
    }
}

// QKV: grid (8,32,3), 128x128 tiles. XCD-chunked swizzle (768 = 8*96).
__global__ __launch_bounds__(256) void gemm_qkv(
    const unsigned short* __restrict__ Aq, const unsigned short* __restrict__ Ak,
    const unsigned short* __restrict__ Av,
    const unsigned short* __restrict__ Bq, const unsigned short* __restrict__ Bk,
    const unsigned short* __restrict__ Bv,
    const float* __restrict__ bq, const float* __restrict__ bk, const float* __restrict__ bv,
    unsigned short* __restrict__ Qh, unsigned short* __restrict__ Kh,
    unsigned short* __restrict__ Vt) {
  int id = (blockIdx.z * 32 + blockIdx.y) * 8 + blockIdx.x;
  int wg = (id & 7) * 96 + (id >> 3);
  int bx = wg & 7, by = (wg >> 3) & 31, bz = wg >> 8;
  const unsigned short* A = (bz == 0) ? Aq : (bz == 1) ? Ak : Av;
  const unsigned short* Bh = (bz == 0) ? Bq : (bz == 1) ? Bk : Bv;
  const float* bias = (bz == 0) ? bq : (bz == 1) ? bk : bv;
  gemm_body<0, 1, 2, 2, 128>(A, Bh, nullptr, bias,
                             (bz == 0) ? Qh : (bz == 1) ? Kh : nullptr,
                             nullptr, (bz == 2) ? Vt : nullptr,
                             by * 128, bx * 128);
}

// Out-proj: grid (16,32), 128x64 tiles, 1-term (plain bf16). 512 = 8*64.
__global__ __launch_bounds__(256) void gemm_out(
    const unsigned short* __restrict__ Ah,
    const unsigned short* __restrict__ Bh,
    const float* __restrict__ bias, float* __restrict__ Cf) {
  int id = blockIdx.y * 16 + blockIdx.x;
  int wg = (id & 7) * 64 + (id >> 3);
  int bx = wg & 15, by = wg >> 4;
  gemm_body<1, 1, 4, 1, 64>(Ah, Bh, nullptr, bias, nullptr, Cf, nullptr,
                            by * 128, bx * 64);
}

// ---------------- flash attention, split-K (z = key half) ----------------
// Fixed-max softmax (m=12 in MFMA C-init) -> partials additive across z.
// K rows staged PERMUTED in LDS so QK^T's C/D layout IS PV's B-fragment
// layout (P never leaves registers). rs via ones-row MFMA.
// grid (16,32,2) XCD-swizzled in (x,y); block 512 = 8 waves.
__global__ __launch_bounds__(512) void attn_fwd(
    const unsigned short* __restrict__ qhi, const unsigned short* __restrict__ khi,
    const unsigned short* __restrict__ vthi,
    const unsigned long long* __restrict__ pm,
    float* __restrict__ po0, float* __restrict__ po1,
    float* __restrict__ pl) {
  __shared__ alignas(16) unsigned short sK[2][64 * 64];
  __shared__ alignas(16) unsigned short sV[2][64 * 64];

  const int tid = threadIdx.x;
  const int lane = tid & 63, wid = tid >> 6;
  const int lr = lane & 15, lg = lane >> 4;
  int id = blockIdx.y * 16 + blockIdx.x;
  int wg = (id & 7) * 64 + (id >> 3);
  const int qblk = wg & 15, bh = wg >> 4;
  const int b = bh >> 4, h = bh & 15;
  const int qw = qblk * 128 + wid * 16;
  const int zz = blockIdx.z;
  const int kt0 = zz * 16;  // tile offset within the 32 64-key tiles

  // staging: thread stages LDS row r0 (0..63 across 8 waves), slot lane&7.
  const int r0 = wid * 8 + (lane >> 3);
  const int scb = (lane & 7) ^ (r0 & 7);
  auto perm = [](int r) {
    int tn = r >> 4, g = (r >> 2) & 3, i = r & 3;
    return (tn >> 1) * 32 + g * 8 + (tn & 1) * 4 + i;
  };
  const unsigned short* kS = khi + ((long)bh * T_SEQ + perm(r0)) * DK + scb * 8;
  const unsigned short* vS = vthi + ((long)bh * DK + r0) * T_SEQ + scb * 8;

  // Q fragment, pre-scaled by C = (1/8)*log2(e)
  const float C = 0.125f * 1.44269504f;
  bf16x8 aqh[2];
  {
    const unsigned short* qp = qhi + ((long)bh * T_SEQ + qw + lr) * DK + lg * 8;
    aqh[0] = *(const bf16x8*)qp;
    aqh[1] = *(const bf16x8*)(qp + 32);
#pragma unroll
    for (int ks = 0; ks < 2; ++ks)
#pragma unroll
      for (int j = 0; j < 8; ++j)
        aqh[ks][j] = (short)f2bf(bf2f((unsigned short)aqh[ks][j]) * C);
  }
  bf16x8 vone;
#pragma unroll
  for (int j = 0; j < 8; ++j) vone[j] = (short)0x3F80;  // bf16 1.0

  const unsigned long long* pmrow = pm + ((long)b * T_SEQ + qw + lr) * 32;
  f32x4 accO[4];  // accO[dn][i] = O[d = dn*16+lg*4+i][q = qw+lr]
  f32x4 accL = (f32x4){0.f, 0.f, 0.f, 0.f};  // ones-row: accL[*] = sum_k P[q]
#pragma unroll
  for (int i = 0; i < 4; ++i) accO[i] = (f32x4){0.f, 0.f, 0.f, 0.f};

  auto stage = [&](int bi, int kb) {
    gload16(kS + (long)kb * DK, &sK[bi][wid * 512]);
    gload16(vS + kb, &sV[bi][wid * 512]);
  };

  stage(0, kt0 * 64);
  __syncthreads();
  int buf = 0;
  unsigned long long pmv = pmrow[kt0];

  for (int kt = 0; kt < 16; ++kt) {
    if (kt < 15) stage(buf ^ 1, (kt0 + kt + 1) * 64);
    unsigned long long pmn = pmrow[kt0 + ((kt + 1) & 15)];  // prefetch

    // S (k-permuted): s[tn][i] = S[q=lr][k=(tn>>1)*32+lg*8+(tn&1)*4+i] - 12
    f32x4 s[4];
    __builtin_amdgcn_s_setprio(1);
#pragma unroll
    for (int tn = 0; tn < 4; ++tn) {
      f32x4 a = (f32x4){-12.f, -12.f, -12.f, -12.f};
#pragma unroll
      for (int ks = 0; ks < 2; ++ks) {
        int r = tn * 16 + lr;
        int idx = r * 64 + (((ks * 4 + lg) ^ (r & 7)) << 3);
        bf16x8 khf = *(const bf16x8*)&sK[buf][idx];
        a = __builtin_amdgcn_mfma_f32_16x16x32_bf16(khf, aqh[ks], a, 0, 0, 0);
      }
      s[tn] = a;
    }
    __builtin_amdgcn_s_setprio(0);

    // mask (permuted bit indices) + exp2 + in-register pack
    unsigned int mlo = (unsigned int)(pmv >> (lg * 8));        // tn=0,1
    unsigned int mhi = (unsigned int)(pmv >> (lg * 8 + 32));   // tn=2,3
    float p[4][4];
#pragma unroll
    for (int tn = 0; tn < 4; ++tn) {
      unsigned int mm = (tn & 2) ? mhi : mlo;
#pragma unroll
      for (int i = 0; i < 4; ++i) {
        float sv = ((mm >> ((tn & 1) * 4 + i)) & 1u) ? -1e30f : s[tn][i];
        p[tn][i] = __builtin_amdgcn_exp2f(sv);
      }
    }
    bf16x8 bp[2];
#pragma unroll
    for (int ks2 = 0; ks2 < 2; ++ks2) {
      u32x4 t;
      t[0] = cvtpk(p[2 * ks2][0], p[2 * ks2][1]);
      t[1] = cvtpk(p[2 * ks2][2], p[2 * ks2][3]);
      t[2] = cvtpk(p[2 * ks2 + 1][0], p[2 * ks2 + 1][1]);
      t[3] = cvtpk(p[2 * ks2 + 1][2], p[2 * ks2 + 1][3]);
      bp[ks2] = *(bf16x8*)&t;
    }

    // O^T += V^T P^T; row-sum via ones-row MFMA (matrix pipe, not VALU)
    __builtin_amdgcn_s_setprio(1);
#pragma unroll
    for (int ks2 = 0; ks2 < 2; ++ks2) {
      accL = __builtin_amdgcn_mfma_f32_16x16x32_bf16(vone, bp[ks2], accL, 0, 0, 0);
#pragma unroll
      for (int dn = 0; dn < 4; ++dn) {
        int rr = dn * 16 + lr;
        int idx = rr * 64 + (((ks2 * 4 + lg) ^ (rr & 7)) << 3);
        bf16x8 vh = *(const bf16x8*)&sV[buf][idx];
        accO[dn] = __builtin_amdgcn_mfma_f32_16x16x32_bf16(vh, bp[ks2], accO[dn], 0, 0, 0);
      }
    }
    __builtin_amdgcn_s_setprio(0);
    __syncthreads();
    buf ^= 1;
    pmv = pmn;
  }

  // write f32 partials (additive across z since m is fixed)
  {
    int q = qw + lr;
    float* pob = (zz ? po1 : po0) + ((long)(b * T_SEQ + q)) * DM + h * DK;
#pragma unroll
    for (int dn = 0; dn < 4; ++dn)
      *(f32x4*)(pob + dn * 16 + lg * 4) = accO[dn];
    if (lg == 0) pl[((long)(zz * 32 + bh)) * T_SEQ + q] = accL[0];
  }
}

// ---------------- combine partials -> bf16 O ----------------
// grid 4096 x 256 threads; each thread: 4 f32 per half -> 4 bf16 out.
__global__ __launch_bounds__(256) void reduce_o(
    const float* __restrict__ po0, const float* __restrict__ po1,
    const float* __restrict__ pl, unsigned short* __restrict__ ohi) {
  const long e = ((long)blockIdx.x * 256 + threadIdx.x) * 4;  // f32 offset
  const int b = (int)(e >> 21);
  const int rem = (int)(e & ((1 << 21) - 1));
  const int q = rem >> 10;
  const int h = (rem & 1023) >> 6;
  const int bh = b * NH + h;
  const float l0 = pl[(long)bh * T_SEQ + q];
  const float l1 = pl[(long)(32 + bh) * T_SEQ + q];
  const float inv = 1.0f / fmaxf(l0 + l1, 1e-30f);
  f32x4 a = *(const f32x4*)(po0 + e);
  f32x4 c = *(const f32x4*)(po1 + e);
#pragma unroll
  for (int j = 0; j < 4; ++j) a[j] = (a[j] + c[j]) * inv;
  uint2 w = make_uint2(cvtpk(a[0], a[1]), cvtpk(a[2], a[3]));
  *(uint2*)(ohi + e) = w;
}

// ---------------- orchestration ----------------
extern "C" void kernel_launch(void* const* d_in, const int* in_sizes, int n_in,
                              void* d_out, int out_size, void* d_ws, size_t ws_size,
                              hipStream_t stream) {
  const float* query = (const float*)d_in[0];
  const float* key_i = (const float*)d_in[1];
  const float* value = (const float*)d_in[2];
  const int* kpm = (const int*)d_in[3];
  const int* am = (const int*)d_in[4];
  const float* Wq = (const float*)d_in[5];
  const float* bq = (const float*)d_in[6];
  const float* Wk = (const float*)d_in[7];
  const float* bk = (const float*)d_in[8];
  const float* Wv = (const float*)d_in[9];
  const float* bv = (const float*)d_in[10];
  const float* Wo = (const float*)d_in[11];
  const float* bo = (const float*)d_in[12];
  float* out = (float*)d_out;

  const size_t MB = 1024ull * 1024ull;
  char* ws = (char*)d_ws;
  if (ws_size < 77 * MB) return;  // insufficient scratch -> leave poison (loud fail)

  unsigned short* qbf = (unsigned short*)(ws + 0 * MB);
  unsigned short* kbf = (unsigned short*)(ws + 8 * MB);
  unsigned short* vbf = (unsigned short*)(ws + 16 * MB);
  unsigned short* q_hi = (unsigned short*)(ws + 24 * MB);
  unsigned short* k_hi = (unsigned short*)(ws + 32 * MB);
  unsigned short* vt_hi = (unsigned short*)(ws + 40 * MB);
  unsigned short* wq_hi = (unsigned short*)(ws + 48 * MB);
  unsigned short* wk_hi = (unsigned short*)(ws + 50 * MB);
  unsigned short* wv_hi = (unsigned short*)(ws + 52 * MB);
  unsigned short* wo_hi = (unsigned short*)(ws + 54 * MB);
  unsigned long long* pmask = (unsigned long long*)(ws + 58 * MB);  // 1MB
  // split-K partials (producers dead before re-use):
  float* po0 = (float*)(ws + 0 * MB);    // 16MB, over qbf/kbf (dead post-QKV)
  float* pl = (float*)(ws + 16 * MB);    // 512KB, over vbf (dead post-QKV)
  unsigned short* o_hi = (unsigned short*)(ws + 24 * MB);  // over q_hi (dead post-attn)
  float* po1 = (float*)(ws + 60 * MB);   // 16MB fresh region

  dim3 blk(256);
  prep_all<<<dim3(49152), blk, 0, stream>>>(
      Wq, Wk, Wv, Wo, query, key_i, value, am, kpm,
      wq_hi, wk_hi, wv_hi, wo_hi, qbf, kbf, vbf, pmask);

  gemm_qkv<<<dim3(8, 32, 3), blk, 0, stream>>>(
      qbf, kbf, vbf, wq_hi, wk_hi, wv_hi, bq, bk, bv, q_hi, k_hi, vt_hi);

  attn_fwd<<<dim3(16, 32, 2), dim3(512), 0, stream>>>(
      q_hi, k_hi, vt_hi, pmask, po0, po1, pl);

  reduce_o<<<dim3(4096), blk, 0, stream>>>(po0, po1, pl, o_hi);

  gemm_out<<<dim3(16, 32), blk, 0, stream>>>(o_hi, wo_hi, bo, out);
}

// Round 20
// 143.874 us; speedup vs baseline: 1.0913x; 1.0913x over previous
//
#include <hip/hip_runtime.h>

// MHA: out = softmax(mask(QK^T/8)) V, with Q/K/V/out linear projections.
// B=2, T=2048, D=1024, H=16, d_k=64.
// R20: REVERT to R18 (best green, 144.6us). R19's split-K was a null:
//      occupancy% unchanged (37%) at 2x blocks/CU -> achieved occupancy is
//      structural (barrier'd 2-phase loop), not resident-wave-limited; the
//      partial-sum traffic + reduce kernel were pure cost. Lever inventory
//      for attn is exhausted within this loop's constraints.

#define T_SEQ 2048
#define NH 16
#define DM 1024
#define DK 64

typedef __attribute__((ext_vector_type(8))) short bf16x8;
typedef __attribute__((ext_vector_type(4))) float f32x4;
typedef __attribute__((ext_vector_type(4))) unsigned short u16x4;
typedef __attribute__((ext_vector_type(4))) unsigned int u32x4;

__device__ __forceinline__ unsigned short f2bf(float x) {
  union { float f; unsigned int u; } v; v.f = x;
  unsigned int r = v.u + 0x7fffu + ((v.u >> 16) & 1u);  // RNE
  return (unsigned short)(r >> 16);
}
__device__ __forceinline__ float bf2f(unsigned short h) {
  union { unsigned int u; float f; } v; v.u = ((unsigned int)h) << 16;
  return v.f;
}
__device__ __forceinline__ void gload16(const unsigned short* g, unsigned short* l) {
  __builtin_amdgcn_global_load_lds(
      (const __attribute__((address_space(1))) void*)(g),
      (__attribute__((address_space(3))) void*)(l), 16, 0, 0);
}
__device__ __forceinline__ unsigned int cvtpk(float a, float b) {
  unsigned int r;
  asm("v_cvt_pk_bf16_f32 %0, %1, %2" : "=v"(r) : "v"(a), "v"(b));
  return r;
}

// ------- fused prep: weights cvt + activations cvt + mask pack -------
// flat grid 49152: id<4096 weights (z=id>>10); id<16384 activations
// (z=(id-4096)>>12); id>=16384 mask-pack (4 ballot rows/block).
__global__ __launch_bounds__(256) void prep_all(
    const float* __restrict__ Wq, const float* __restrict__ Wk,
    const float* __restrict__ Wv, const float* __restrict__ Wo,
    const float* __restrict__ q, const float* __restrict__ k,
    const float* __restrict__ v,
    const int* __restrict__ am, const int* __restrict__ kpm,
    unsigned short* __restrict__ wq, unsigned short* __restrict__ wk,
    unsigned short* __restrict__ wv, unsigned short* __restrict__ woh,
    unsigned short* __restrict__ qb, unsigned short* __restrict__ kb,
    unsigned short* __restrict__ vb,
    unsigned long long* __restrict__ pm) {
  const int id = blockIdx.x;
  if (id < 4096) {
    const int z = id >> 10;
    const int i = (id & 1023) * 256 + threadIdx.x;
    const float* src = (z == 0) ? Wq : (z == 1) ? Wk : (z == 2) ? Wv : Wo;
    unsigned short* dst = (z == 0) ? wq : (z == 1) ? wk : (z == 2) ? wv : woh;
    f32x4 x = ((const f32x4*)src)[i];
    u16x4 h;
#pragma unroll
    for (int j = 0; j < 4; ++j) h[j] = f2bf(x[j]);
    ((u16x4*)dst)[i] = h;
  } else if (id < 16384) {
    const int t = id - 4096;
    const int z = t >> 12;
    const int i = (t & 4095) * 256 + threadIdx.x;
    const float* src = (z == 0) ? q : (z == 1) ? k : v;
    unsigned short* dst = (z == 0) ? qb : (z == 1) ? kb : vb;
    f32x4 x = ((const f32x4*)src)[i];
    u16x4 h;
#pragma unroll
    for (int j = 0; j < 4; ++j) h[j] = f2bf(x[j]);
    ((u16x4*)dst)[i] = h;
  } else {
    const int w = (id - 16384) * 4 + ((int)threadIdx.x >> 6);
    const int lane = threadIdx.x & 63;
    const int kt = w & 31;
    const int qq = (w >> 5) & 2047;
    const int b = w >> 16;
    const int col = kt * 64 + lane;
    int masked = am[((long)(b * T_SEQ + qq)) * T_SEQ + col] | kpm[b * T_SEQ + col];
    unsigned long long bits = __ballot(masked != 0);
    if (lane == 0) pm[((long)(b * T_SEQ + qq)) * 32 + kt] = bits;
  }
}

// ---------------- GEMM: C = A @ B^T + bias (A,B bf16 in HBM) --------------
template <int EPI, int TERMS, int WM, int WN, int BN>
__device__ __forceinline__ void gemm_body(
    const unsigned short* __restrict__ Ahi,
    const unsigned short* __restrict__ Bhi, const unsigned short* __restrict__ Blo,
    const float* __restrict__ bias, unsigned short* __restrict__ Chi,
    float* __restrict__ Cf, unsigned short* __restrict__ Vt, int m0, int n0) {
  constexpr int FM = 128 / (WM * 16);
  constexpr int FN = BN / (WN * 16);
  constexpr int AIT = 2;
  constexpr int BIT = (BN * 4) / 256;
  __shared__ alignas(16) unsigned short sAh[2][128 * 32];
  __shared__ alignas(16) unsigned short sBh[2][BN * 32];
  __shared__ alignas(16) unsigned short sBl[TERMS == 2 ? 2 : 1][TERMS == 2 ? BN * 32 : 8];

  const int tid = threadIdx.x;
  const int lane = tid & 63, wid = tid >> 6;
  const int lr = lane & 15, lg = lane >> 4;
  const int wr = wid / WN, wc = wid % WN;

  f32x4 acc[FM][FN];
#pragma unroll
  for (int i = 0; i < FM; ++i)
#pragma unroll
    for (int j = 0; j < FN; ++j) acc[i][j] = (f32x4){0.f, 0.f, 0.f, 0.f};

  long asrc[AIT], bsrc[BIT];
#pragma unroll
  for (int it = 0; it < AIT; ++it) {
    int c = it * 256 + tid, r = c >> 2;
    int scb = (c & 3) ^ ((r >> 1) & 3);
    asrc[it] = (long)(m0 + r) * DM + scb * 8;
  }
#pragma unroll
  for (int it = 0; it < BIT; ++it) {
    int c = it * 256 + tid, r = c >> 2;
    int scb = (c & 3) ^ ((r >> 1) & 3);
    bsrc[it] = (long)(n0 + r) * DM + scb * 8;
  }

  auto stage = [&](int bi, int kt) {
#pragma unroll
    for (int it = 0; it < AIT; ++it)
      gload16(Ahi + asrc[it] + kt * 32, &sAh[bi][it * 2048 + wid * 512]);
#pragma unroll
    for (int it = 0; it < BIT; ++it) {
      const int dst = it * 2048 + wid * 512;
      gload16(Bhi + bsrc[it] + kt * 32, &sBh[bi][dst]);
      if constexpr (TERMS == 2) gload16(Blo + bsrc[it] + kt * 32, &sBl[bi][dst]);
    }
  };

  stage(0, 0);
  __syncthreads();
  int buf = 0;

  for (int kt = 0; kt < DM / 32; ++kt) {
    if (kt < DM / 32 - 1) stage(buf ^ 1, kt + 1);

    bf16x8 afh[FM], bfh[FN], bfl[FN];
#pragma unroll
    for (int f = 0; f < FM; ++f) {
      int rA = wr * (FM * 16) + f * 16 + lr;
      int iA = rA * 32 + ((lg ^ ((rA >> 1) & 3)) << 3);
      afh[f] = *(const bf16x8*)&sAh[buf][iA];
    }
#pragma unroll
    for (int f = 0; f < FN; ++f) {
      int rB = wc * (FN * 16) + f * 16 + lr;
      int iB = rB * 32 + ((lg ^ ((rB >> 1) & 3)) << 3);
      bfh[f] = *(const bf16x8*)&sBh[buf][iB];
      if constexpr (TERMS == 2) bfl[f] = *(const bf16x8*)&sBl[buf][iB];
    }
#pragma unroll
    for (int fm = 0; fm < FM; ++fm)
#pragma unroll
      for (int fn = 0; fn < FN; ++fn) {
        acc[fm][fn] = __builtin_amdgcn_mfma_f32_16x16x32_bf16(afh[fm], bfh[fn], acc[fm][fn], 0, 0, 0);
        if constexpr (TERMS == 2)
          acc[fm][fn] = __builtin_amdgcn_mfma_f32_16x16x32_bf16(afh[fm], bfl[fn], acc[fm][fn], 0, 0, 0);
      }
    __syncthreads();
    buf ^= 1;
  }

#pragma unroll
  for (int fm = 0; fm < FM; ++fm)
#pragma unroll
    for (int fn = 0; fn < FN; ++fn) {
      const int mb = m0 + wr * (FM * 16) + fm * 16 + lg * 4;
      const int n = n0 + wc * (FN * 16) + fn * 16 + lr;
      float y[4];
#pragma unroll
      for (int i = 0; i < 4; ++i) y[i] = acc[fm][fn][i] + bias[n];
      if constexpr (EPI == 0) {
        if (Vt) {
          // V^T: [bh][d][t], 4 consecutive t -> one 8B store
          int b = mb >> 11, t0 = mb & 2047, hh_ = n >> 6, d = n & 63;
          uint2 w = make_uint2(cvtpk(y[0], y[1]), cvtpk(y[2], y[3]));
          *(uint2*)(Vt + ((long)((b * NH + hh_) * DK + d)) * T_SEQ + t0) = w;
        } else {
#pragma unroll
          for (int i = 0; i < 4; ++i) {
            int m = mb + i;
            int b = m >> 11, t = m & 2047, hh_ = n >> 6, d = n & 63;
            Chi[((long)((b * NH + hh_) * T_SEQ + t)) * DK + d] = f2bf(y[i]);
          }
        }
      } else {
#pragma unroll
        for (int i = 0; i < 4; ++i) Cf[(long)(mb + i) * DM + n] = y[i];
      }
    }
}

// QKV: grid (8,32,3), 128x128 tiles. XCD-chunked swizzle (768 = 8*96).
__global__ __launch_bounds__(256) void gemm_qkv(
    const unsigned short* __restrict__ Aq, const unsigned short* __restrict__ Ak,
    const unsigned short* __restrict__ Av,
    const unsigned short* __restrict__ Bq, const unsigned short* __restrict__ Bk,
    const unsigned short* __restrict__ Bv,
    const float* __restrict__ bq, const float* __restrict__ bk, const float* __restrict__ bv,
    unsigned short* __restrict__ Qh, unsigned short* __restrict__ Kh,
    unsigned short* __restrict__ Vt) {
  int id = (blockIdx.z * 32 + blockIdx.y) * 8 + blockIdx.x;
  int wg = (id & 7) * 96 + (id >> 3);
  int bx = wg & 7, by = (wg >> 3) & 31, bz = wg >> 8;
  const unsigned short* A = (bz == 0) ? Aq : (bz == 1) ? Ak : Av;
  const unsigned short* Bh = (bz == 0) ? Bq : (bz == 1) ? Bk : Bv;
  const float* bias = (bz == 0) ? bq : (bz == 1) ? bk : bv;
  gemm_body<0, 1, 2, 2, 128>(A, Bh, nullptr, bias,
                             (bz == 0) ? Qh : (bz == 1) ? Kh : nullptr,
                             nullptr, (bz == 2) ? Vt : nullptr,
                             by * 128, bx * 128);
}

// Out-proj: grid (16,32), 128x64 tiles, 1-term (plain bf16). 512 = 8*64.
__global__ __launch_bounds__(256) void gemm_out(
    const unsigned short* __restrict__ Ah,
    const unsigned short* __restrict__ Bh,
    const float* __restrict__ bias, float* __restrict__ Cf) {
  int id = blockIdx.y * 16 + blockIdx.x;
  int wg = (id & 7) * 64 + (id >> 3);
  int bx = wg & 15, by = wg >> 4;
  gemm_body<1, 1, 4, 1, 64>(Ah, Bh, nullptr, bias, nullptr, Cf, nullptr,
                            by * 128, bx * 64);
}

// ---------------- flash attention (R12/R18 shape) ----------------
// Fixed-max softmax (m=12 in MFMA C-init). K rows staged PERMUTED in LDS so
// QK^T's C/D layout IS PV's B-fragment layout (P never leaves registers).
// rs computed on the matrix pipe: accL = mfma(ones, bp, accL).
// grid (16,32) XCD-swizzled; block 512 = 8 waves; wave owns 16 q-rows.
__global__ __launch_bounds__(512) void attn_fwd(
    const unsigned short* __restrict__ qhi, const unsigned short* __restrict__ khi,
    const unsigned short* __restrict__ vthi,
    const unsigned long long* __restrict__ pm,
    unsigned short* __restrict__ ohi) {
  __shared__ alignas(16) unsigned short sK[2][64 * 64];
  __shared__ alignas(16) unsigned short sV[2][64 * 64];

  const int tid = threadIdx.x;
  const int lane = tid & 63, wid = tid >> 6;
  const int lr = lane & 15, lg = lane >> 4;
  int id = blockIdx.y * 16 + blockIdx.x;
  int wg = (id & 7) * 64 + (id >> 3);
  const int qblk = wg & 15, bh = wg >> 4;
  const int b = bh >> 4, h = bh & 15;
  const int qw = qblk * 128 + wid * 16;

  // staging: thread stages LDS row r0 (0..63 across 8 waves), slot lane&7.
  const int r0 = wid * 8 + (lane >> 3);
  const int scb = (lane & 7) ^ (r0 & 7);
  auto perm = [](int r) {
    int tn = r >> 4, g = (r >> 2) & 3, i = r & 3;
    return (tn >> 1) * 32 + g * 8 + (tn & 1) * 4 + i;
  };
  const unsigned short* kS = khi + ((long)bh * T_SEQ + perm(r0)) * DK + scb * 8;
  const unsigned short* vS = vthi + ((long)bh * DK + r0) * T_SEQ + scb * 8;

  // Q fragment, pre-scaled by C = (1/8)*log2(e)
  const float C = 0.125f * 1.44269504f;
  bf16x8 aqh[2];
  {
    const unsigned short* qp = qhi + ((long)bh * T_SEQ + qw + lr) * DK + lg * 8;
    aqh[0] = *(const bf16x8*)qp;
    aqh[1] = *(const bf16x8*)(qp + 32);
#pragma unroll
    for (int ks = 0; ks < 2; ++ks)
#pragma unroll
      for (int j = 0; j < 8; ++j)
        aqh[ks][j] = (short)f2bf(bf2f((unsigned short)aqh[ks][j]) * C);
  }
  bf16x8 vone;
#pragma unroll
  for (int j = 0; j < 8; ++j) vone[j] = (short)0x3F80;  // bf16 1.0

  const unsigned long long* pmrow = pm + ((long)b * T_SEQ + qw + lr) * 32;
  f32x4 accO[4];  // accO[dn][i] = O[d = dn*16+lg*4+i][q = qw+lr]
  f32x4 accL = (f32x4){0.f, 0.f, 0.f, 0.f};  // ones-row: accL[*] = sum_k P[q]
#pragma unroll
  for (int i = 0; i < 4; ++i) accO[i] = (f32x4){0.f, 0.f, 0.f, 0.f};

  auto stage = [&](int bi, int kb) {
    gload16(kS + (long)kb * DK, &sK[bi][wid * 512]);
    gload16(vS + kb, &sV[bi][wid * 512]);
  };

  stage(0, 0);
  __syncthreads();
  int buf = 0;
  unsigned long long pmv = pmrow[0];

  for (int kt = 0; kt < T_SEQ / 64; ++kt) {
    if (kt < T_SEQ / 64 - 1) stage(buf ^ 1, (kt + 1) * 64);
    unsigned long long pmn = pmrow[(kt + 1) & 31];  // prefetch next tile's mask

    // S (k-permuted): s[tn][i] = S[q=lr][k=(tn>>1)*32+lg*8+(tn&1)*4+i] - 12
    f32x4 s[4];
    __builtin_amdgcn_s_setprio(1);
#pragma unroll
    for (int tn = 0; tn < 4; ++tn) {
      f32x4 a = (f32x4){-12.f, -12.f, -12.f, -12.f};
#pragma unroll
      for (int ks = 0; ks < 2; ++ks) {
        int r = tn * 16 + lr;
        int idx = r * 64 + (((ks * 4 + lg) ^ (r & 7)) << 3);
        bf16x8 khf = *(const bf16x8*)&sK[buf][idx];
        a = __builtin_amdgcn_mfma_f32_16x16x32_bf16(khf, aqh[ks], a, 0, 0, 0);
      }
      s[tn] = a;
    }
    __builtin_amdgcn_s_setprio(0);

    // mask (permuted bit indices) + exp2 + in-register pack
    unsigned int mlo = (unsigned int)(pmv >> (lg * 8));        // tn=0,1
    unsigned int mhi = (unsigned int)(pmv >> (lg * 8 + 32));   // tn=2,3
    float p[4][4];
#pragma unroll
    for (int tn = 0; tn < 4; ++tn) {
      unsigned int mm = (tn & 2) ? mhi : mlo;
#pragma unroll
      for (int i = 0; i < 4; ++i) {
        float sv = ((mm >> ((tn & 1) * 4 + i)) & 1u) ? -1e30f : s[tn][i];
        p[tn][i] = __builtin_amdgcn_exp2f(sv);
      }
    }
    bf16x8 bp[2];
#pragma unroll
    for (int ks2 = 0; ks2 < 2; ++ks2) {
      u32x4 t;
      t[0] = cvtpk(p[2 * ks2][0], p[2 * ks2][1]);
      t[1] = cvtpk(p[2 * ks2][2], p[2 * ks2][3]);
      t[2] = cvtpk(p[2 * ks2 + 1][0], p[2 * ks2 + 1][1]);
      t[3] = cvtpk(p[2 * ks2 + 1][2], p[2 * ks2 + 1][3]);
      bp[ks2] = *(bf16x8*)&t;
    }

    // O^T += V^T P^T; row-sum via ones-row MFMA (matrix pipe, not VALU)
    __builtin_amdgcn_s_setprio(1);
#pragma unroll
    for (int ks2 = 0; ks2 < 2; ++ks2) {
      accL = __builtin_amdgcn_mfma_f32_16x16x32_bf16(vone, bp[ks2], accL, 0, 0, 0);
#pragma unroll
      for (int dn = 0; dn < 4; ++dn) {
        int rr = dn * 16 + lr;
        int idx = rr * 64 + (((ks2 * 4 + lg) ^ (rr & 7)) << 3);
        bf16x8 vh = *(const bf16x8*)&sV[buf][idx];
        accO[dn] = __builtin_amdgcn_mfma_f32_16x16x32_bf16(vh, bp[ks2], accO[dn], 0, 0, 0);
      }
    }
    __builtin_amdgcn_s_setprio(0);
    __syncthreads();
    buf ^= 1;
    pmv = pmn;
  }

  // normalize + write O (single bf16) at [b,q,h*64+d]; accL[0] = full row-sum
  {
    float inv = 1.0f / fmaxf(accL[0], 1e-30f);
    int q = qw + lr;
    long obase = ((long)(b * T_SEQ + q)) * DM + h * DK;
#pragma unroll
    for (int dn = 0; dn < 4; ++dn) {
      f32x4 vv = accO[dn];
      vv *= inv;
      uint2 w = make_uint2(cvtpk(vv[0], vv[1]), cvtpk(vv[2], vv[3]));
      *(uint2*)(ohi + obase + dn * 16 + lg * 4) = w;
    }
  }
}

// ---------------- orchestration ----------------
extern "C" void kernel_launch(void* const* d_in, const int* in_sizes, int n_in,
                              void* d_out, int out_size, void* d_ws, size_t ws_size,
                              hipStream_t stream) {
  const float* query = (const float*)d_in[0];
  const float* key_i = (const float*)d_in[1];
  const float* value = (const float*)d_in[2];
  const int* kpm = (const int*)d_in[3];
  const int* am = (const int*)d_in[4];
  const float* Wq = (const float*)d_in[5];
  const float* bq = (const float*)d_in[6];
  const float* Wk = (const float*)d_in[7];
  const float* bk = (const float*)d_in[8];
  const float* Wv = (const float*)d_in[9];
  const float* bv = (const float*)d_in[10];
  const float* Wo = (const float*)d_in[11];
  const float* bo = (const float*)d_in[12];
  float* out = (float*)d_out;

  const size_t MB = 1024ull * 1024ull;
  char* ws = (char*)d_ws;
  if (ws_size < 60 * MB) return;  // insufficient scratch -> leave poison (loud fail)

  unsigned short* qbf = (unsigned short*)(ws + 0 * MB);
  unsigned short* kbf = (unsigned short*)(ws + 8 * MB);
  unsigned short* vbf = (unsigned short*)(ws + 16 * MB);
  unsigned short* q_hi = (unsigned short*)(ws + 24 * MB);
  unsigned short* k_hi = (unsigned short*)(ws + 32 * MB);
  unsigned short* vt_hi = (unsigned short*)(ws + 40 * MB);
  unsigned short* wq_hi = (unsigned short*)(ws + 48 * MB);
  unsigned short* wk_hi = (unsigned short*)(ws + 50 * MB);
  unsigned short* wv_hi = (unsigned short*)(ws + 52 * MB);
  unsigned short* wo_hi = (unsigned short*)(ws + 54 * MB);
  unsigned long long* pmask = (unsigned long long*)(ws + 58 * MB);  // 1MB, no alias
  // alias (producer dead before re-use):
  unsigned short* o_hi = qbf;  // after gemm_qkv

  dim3 blk(256);
  prep_all<<<dim3(49152), blk, 0, stream>>>(
      Wq, Wk, Wv, Wo, query, key_i, value, am, kpm,
      wq_hi, wk_hi, wv_hi, wo_hi, qbf, kbf, vbf, pmask);

  gemm_qkv<<<dim3(8, 32, 3), blk, 0, stream>>>(
      qbf, kbf, vbf, wq_hi, wk_hi, wv_hi, bq, bk, bv, q_hi, k_hi, vt_hi);

  attn_fwd<<<dim3(16, 32), dim3(512), 0, stream>>>(q_hi, k_hi, vt_hi, pmask, o_hi);

  gemm_out<<<dim3(16, 32), blk, 0, stream>>>(o_hi, wo_hi, bo, out);
}